// Round 7
// baseline (312.981 us; speedup 1.0000x reference)
//
#include <hip/hip_runtime.h>
#include <hip/hip_bf16.h>
#include <math.h>

#define NPERSEG 128
#define HOP     64
#define NFRAMES 33
#define NFREQ   65
#define BATCH   2048
#define LEN     2048
#define NSENS   8
#define FEAT    (NFREQ * NFRAMES)   // 2145
#define FEATP   2176                // FEAT padded to multiple of 64
#define H1      1024
#define H2      512
#define H3      256
#define NOUT    10

// STFT-as-GEMM geometry
#define XROW    2264                // elems/row; 1132 words % 32 = 12
#define MT_PER_WAVE 3
#define NCWS    (10 * 4 * 64 * 8)   // 20480 basis elems, fragment-ordered

typedef __attribute__((ext_vector_type(8))) short short8;     // 8 bf16 = 4 VGPRs
typedef __attribute__((ext_vector_type(4))) float float4v;    // MFMA C/D
typedef unsigned short ushort;
typedef unsigned int uint;

// Lean RNE fp32->bf16 (no NaN/Inf path — all values here are finite).
__device__ __forceinline__ ushort f2b(float v) {
    union { float f; uint i; } c; c.f = v;
    uint r = c.i + 0x7fffu + ((c.i >> 16) & 1u);
    return (ushort)(r >> 16);
}
__device__ __forceinline__ uint pack2(float a, float b) {
    return (uint)f2b(a) | ((uint)f2b(b) << 16);
}
__device__ __forceinline__ float b2fu(uint lo16) {
    union { uint i; float f; } c; c.i = lo16 << 16; return c.f;
}

// ---------------------------------------------------------------------------
// Kernel 0: fused prep — fragment-ordered DFT basis + 3 fragment-ordered
// weight converts. Fragment order (B operand of 16x16x32 MFMA):
//   buf[(((ntile*KC) + kc)*64 + lane)*8 + j] = W[n][k],
//   n = ntile*16 + (lane&15), k = kc*32 + (lane>>4)*8 + j.
// A GEMM wave then loads its B-frag as one coalesced 16 B/lane read.
// ---------------------------------------------------------------------------
__device__ __forceinline__ void frag_cvt(const float* __restrict__ src,
                                         ushort* __restrict__ dst,
                                         int e, int KC, int Ksrc) {
    int j    = e & 7;
    int lane = (e >> 3) & 63;
    int rest = e >> 9;
    int kc   = rest % KC;
    int nt   = rest / KC;
    int n = nt * 16 + (lane & 15);
    int k = kc * 32 + ((lane >> 4) & 3) * 8 + j;
    dst[e] = f2b(k < Ksrc ? src[(long)n * Ksrc + k] : 0.f);
}

__global__ __launch_bounds__(256)
void sf_prep(const float* __restrict__ W1, const float* __restrict__ W2,
             const float* __restrict__ W3,
             ushort* __restrict__ cws, ushort* __restrict__ W1f,
             ushort* __restrict__ W2f, ushort* __restrict__ W3f) {
    const int N1 = NCWS;
    const int N2 = N1 + (H1 / 16) * (FEATP / 32) * 512;
    const int N3 = N2 + (H2 / 16) * (H1 / 32) * 512;
    const int N4 = N3 + (H3 / 16) * (H2 / 32) * 512;
    int e = blockIdx.x * 256 + threadIdx.x;
    const float STEP = 6.28318530717958647692f / 128.0f;
    if (e < N1) {
        int j = e & 7, l = (e >> 3) & 63, ks = (e >> 9) & 3, tile = e >> 11;
        int n = tile * 16 + (l & 15);
        int k = ks * 32 + (l >> 4) * 8 + j;
        float win = 0.5f - 0.5f * cosf(STEP * (float)k);
        float v = 0.f;
        if (n < NFREQ)
            v = win * cosf(STEP * (float)((n * k) & 127)) * (1.0f / 64.0f);
        else if (n >= 80 && n < 80 + NFREQ)
            v = win * sinf(STEP * (float)(((n - 80) * k) & 127)) * (1.0f / 64.0f);
        cws[e] = f2b(v);
    } else if (e < N2) {
        frag_cvt(W1, W1f, e - N1, FEATP / 32, FEAT);
    } else if (e < N3) {
        frag_cvt(W2, W2f, e - N2, H1 / 32, H1);
    } else if (e < N4) {
        frag_cvt(W3, W3f, e - N3, H2 / 32, H2);
    }
}

// ---------------------------------------------------------------------------
// Kernel 1: STFT magnitude + sensor fusion via MFMA.
// Round-7: lean f2b (4 VALU ops) + hw sqrt (__builtin_amdgcn_sqrtf) — the
// round-6 counters showed VALUBusy 52% from precise-sqrtf + RNE-convert fat.
// Structure (A-staging, frag-ordered cws B-loads, hstage write) verified r6.
// ---------------------------------------------------------------------------
__global__ __launch_bounds__(512, 4)
void sf_stft_fuse(const float* __restrict__ x,
                  const float* __restrict__ sw,
                  const ushort* __restrict__ cws,
                  ushort* __restrict__ h0) {
    __shared__ __align__(16) ushort xbp[NSENS * XROW];   // 36.2 KB
    __shared__ __align__(16) ushort hstage[FEATP];       // 4.4 KB

    const int b    = blockIdx.x;
    const int tid  = threadIdx.x;
    const int lane = tid & 63;
    const int wv   = tid >> 6;

    // ---- x staging: read float4 pairs, pack bf16x2, ds_write_b32
    const float4* xb4 = (const float4*)(x + (size_t)b * (LEN * NSENS));
    uint* xw = (uint*)xbp;
    for (int e = tid; e < 2048; e += 512) {
        int i = e >> 1;            // sample-pair index: l = 2i, 2i+1
        int h = e & 1;             // sensor half: s = 4h..4h+3
        float4 v0 = xb4[i * 4 + h];
        float4 v1 = xb4[i * 4 + 2 + h];
        int base = (h * 4) * (XROW / 2) + 32 + i;
        xw[base                 ] = pack2(v0.x, v1.x);
        xw[base +     (XROW / 2)] = pack2(v0.y, v1.y);
        xw[base + 2 * (XROW / 2)] = pack2(v0.z, v1.z);
        xw[base + 3 * (XROW / 2)] = pack2(v0.w, v1.w);
    }
    for (int e = tid; e < NSENS * 32; e += 512)          // left pad (64 elems)
        xw[(e >> 5) * (XROW / 2) + (e & 31)] = 0;
    for (int e = tid; e < NSENS * 76; e += 512) {        // right pad (152 elems)
        int s = e / 76;
        xw[s * (XROW / 2) + 1056 + (e - s * 76)] = 0;
    }
    if (tid < FEATP - FEAT) hstage[FEAT + tid] = 0;      // zero K-pad cols
    __syncthreads();

    // ---- MFMA phase (re/im pair-structured)
    const int col = lane & 15;
    const int q   = lane >> 4;

    // inline softmax of the 8 sensor weights; this lane needs sensors (q&1)*4..+3
    float wqa[4];
    {
        float s0 = sw[0], s1 = sw[1], s2 = sw[2], s3 = sw[3];
        float s4 = sw[4], s5 = sw[5], s6 = sw[6], s7 = sw[7];
        float mx = fmaxf(fmaxf(fmaxf(s0, s1), fmaxf(s2, s3)),
                         fmaxf(fmaxf(s4, s5), fmaxf(s6, s7)));
        float e0 = expf(s0 - mx), e1 = expf(s1 - mx), e2 = expf(s2 - mx), e3 = expf(s3 - mx);
        float e4 = expf(s4 - mx), e5 = expf(s5 - mx), e6 = expf(s6 - mx), e7 = expf(s7 - mx);
        float inv = 1.0f / (e0 + e1 + e2 + e3 + e4 + e5 + e6 + e7);
        if ((q & 1) == 0) { wqa[0] = e0 * inv; wqa[1] = e1 * inv; wqa[2] = e2 * inv; wqa[3] = e3 * inv; }
        else              { wqa[0] = e4 * inv; wqa[1] = e5 * inv; wqa[2] = e6 * inv; wqa[3] = e7 * inv; }
    }

    const ushort* abase[MT_PER_WAVE];
    #pragma unroll
    for (int mb = 0; mb < MT_PER_WAVE; ++mb) {
        int mi = wv * MT_PER_WAVE + mb;          // 0..23
        int m  = mi * 16 + col;
        int ta = m >> 3; if (ta > NFRAMES) ta = NFRAMES;   // clamp into zero pad
        int sa = m & 7;
        abase[mb] = &xbp[sa * XROW + ta * HOP + q * 8];
    }

    #pragma unroll 1
    for (int np = 0; np < 5; ++np) {             // re tile np, im tile np+5
        float4v accR[MT_PER_WAVE], accI[MT_PER_WAVE];
        #pragma unroll
        for (int mb = 0; mb < MT_PER_WAVE; ++mb) {
            accR[mb] = (float4v){0.f, 0.f, 0.f, 0.f};
            accI[mb] = (float4v){0.f, 0.f, 0.f, 0.f};
        }
        #pragma unroll
        for (int ks = 0; ks < 4; ++ks) {
            short8 bR = *(const short8*)&cws[(((np * 4) + ks) * 64 + lane) * 8];
            short8 bI = *(const short8*)&cws[((((np + 5) * 4) + ks) * 64 + lane) * 8];
            #pragma unroll
            for (int mb = 0; mb < MT_PER_WAVE; ++mb) {
                short8 af = *(const short8*)(abase[mb] + ks * 32);
                accR[mb] = __builtin_amdgcn_mfma_f32_16x16x32_bf16(af, bR, accR[mb], 0, 0, 0);
                accI[mb] = __builtin_amdgcn_mfma_f32_16x16x32_bf16(af, bI, accI[mb], 0, 0, 0);
            }
        }
        int f = np * 16 + col;
        #pragma unroll
        for (int mb = 0; mb < MT_PER_WAVE; ++mb) {
            float ps = 0.f;
            #pragma unroll
            for (int r = 0; r < 4; ++r) {
                float re = accR[mb][r];
                float im = accI[mb][r];
                ps += wqa[r] * __builtin_amdgcn_sqrtf(re * re + im * im);
            }
            float tot = ps + __shfl_xor(ps, 16, 64);
            int mi = wv * MT_PER_WAVE + mb;
            int t  = mi * 2 + (q >> 1);
            if (((q & 1) == 0) && t < NFRAMES && f < NFREQ)
                hstage[f * NFRAMES + t] = f2b(tot);
        }
    }
    __syncthreads();

    // ---- coalesced h0 write (8 B/lane)
    const uint2* hsw = (const uint2*)hstage;
    uint2* ho = (uint2*)(h0 + (size_t)b * FEATP);
    for (int e = tid; e < FEATP / 4; e += 512)
        ho[e] = hsw[e];
}

// ---------------------------------------------------------------------------
// Kernel 2: LDS-free single-wave "flatmm" NT-GEMM.
// A: linear row-major MxK bf16. Wf: fragment-ordered (see sf_prep).
// Tile = (MT*16) x (NT*16), one wave per block, BK=32 per iteration:
//   A-frag: 16 B/lane from 16 rows (each row's 64 B fully consumed);
//   B-frag: one fully-coalesced 1 KB wave load (L2-hot weights);
//   no LDS, no barriers -> occupancy VGPR-bound (~16 blocks/CU) hides latency.
// M mult of MT*16, N mult of NT*16, K mult of 32. Output bf16 linear.
// ---------------------------------------------------------------------------
template <int MT, int NT, int RELU>
__global__ __launch_bounds__(64)
void sf_gemm_flat(const ushort* __restrict__ A, const ushort* __restrict__ Wf,
                  const float* __restrict__ bias, ushort* __restrict__ C,
                  int M, int N, int K) {
    const int KC = K >> 5;
    const int lane = threadIdx.x;
    const int col  = lane & 15;
    const int q    = lane >> 4;

    const int m0  = blockIdx.y * (MT * 16);
    const int nt0 = blockIdx.x * NT;

    const ushort* ab = A + (size_t)(m0 + col) * K + q * 8;
    const ushort* bb = Wf + ((size_t)nt0 * KC) * 512 + lane * 8;

    float4v acc[MT][NT];
    #pragma unroll
    for (int mi = 0; mi < MT; ++mi)
        #pragma unroll
        for (int ni = 0; ni < NT; ++ni)
            acc[mi][ni] = (float4v){0.f, 0.f, 0.f, 0.f};

    #pragma unroll 2
    for (int kt = 0; kt < KC; ++kt) {
        short8 af[MT], bf[NT];
        #pragma unroll
        for (int mi = 0; mi < MT; ++mi)
            af[mi] = *(const short8*)(ab + (size_t)mi * 16 * K + kt * 32);
        #pragma unroll
        for (int ni = 0; ni < NT; ++ni)
            bf[ni] = *(const short8*)(bb + ((size_t)ni * KC + kt) * 512);
        #pragma unroll
        for (int mi = 0; mi < MT; ++mi)
            #pragma unroll
            for (int ni = 0; ni < NT; ++ni)
                acc[mi][ni] = __builtin_amdgcn_mfma_f32_16x16x32_bf16(
                    af[mi], bf[ni], acc[mi][ni], 0, 0, 0);
    }

    #pragma unroll
    for (int ni = 0; ni < NT; ++ni) {
        int n = nt0 * 16 + ni * 16 + col;
        float bn = bias[n];
        #pragma unroll
        for (int mi = 0; mi < MT; ++mi) {
            int mbase = m0 + mi * 16 + q * 4;
            #pragma unroll
            for (int r = 0; r < 4; ++r) {
                float v = acc[mi][ni][r] + bn;
                if (RELU) v = fmaxf(v, 0.f);
                C[(size_t)(mbase + r) * N + n] = f2b(v);
            }
        }
    }
}

// ---------------------------------------------------------------------------
// Kernel 3: final tiny layer, fp32 out, vectorized loads.
// ---------------------------------------------------------------------------
__global__ __launch_bounds__(256)
void sf_final(const ushort* __restrict__ h3, const float* __restrict__ W4,
              const float* __restrict__ b4, float* __restrict__ out) {
    int o = blockIdx.x * 256 + threadIdx.x;
    if (o >= BATCH * NOUT) return;
    int m = o / NOUT, n = o - m * NOUT;
    const uint2*  av  = (const uint2*)(h3 + (size_t)m * H3);   // 4 bf16 per uint2
    const float4* wv4 = (const float4*)(W4 + (size_t)n * H3);
    float s = 0.f;
    #pragma unroll 8
    for (int j = 0; j < H3 / 4; ++j) {
        uint2 a = av[j];
        float4 w = wv4[j];
        s = fmaf(b2fu(a.x & 0xffffu), w.x, s);
        s = fmaf(b2fu(a.x >> 16),     w.y, s);
        s = fmaf(b2fu(a.y & 0xffffu), w.z, s);
        s = fmaf(b2fu(a.y >> 16),     w.w, s);
    }
    out[o] = s + b4[n];
}

// ---------------------------------------------------------------------------
extern "C" void kernel_launch(void* const* d_in, const int* in_sizes, int n_in,
                              void* d_out, int out_size, void* d_ws, size_t ws_size,
                              hipStream_t stream) {
    const float* x  = (const float*)d_in[0];
    const float* sw = (const float*)d_in[1];
    const float* W1 = (const float*)d_in[2];
    const float* b1 = (const float*)d_in[3];
    const float* W2 = (const float*)d_in[4];
    const float* b2 = (const float*)d_in[5];
    const float* W3 = (const float*)d_in[6];
    const float* b3 = (const float*)d_in[7];
    const float* W4 = (const float*)d_in[8];
    const float* b4 = (const float*)d_in[9];
    float* out = (float*)d_out;

    char* cur = (char*)d_ws;
    ushort* cws  = (ushort*)cur;                cur += (size_t)NCWS * 2;          // 40 KB
    ushort* h0   = (ushort*)cur;                cur += (size_t)BATCH * FEATP * 2; // 8.9 MB
    ushort* W1f  = (ushort*)cur;                cur += (size_t)H1 * FEATP * 2;    // 4.5 MB
    ushort* W2f  = (ushort*)cur;                cur += (size_t)H2 * H1 * 2;       // 1.0 MB
    ushort* W3f  = (ushort*)cur;                cur += (size_t)H3 * H2 * 2;       // 0.3 MB
    ushort* h1   = (ushort*)cur;                cur += (size_t)BATCH * H1 * 2;    // 4.2 MB
    ushort* h2   = (ushort*)cur;                cur += (size_t)BATCH * H2 * 2;    // 2.1 MB
    ushort* h3   = (ushort*)cur;                cur += (size_t)BATCH * H3 * 2;    // 1.0 MB

    const int n_prep = NCWS + H1 * FEATP + H2 * H1 + H3 * H2;
    sf_prep<<<(n_prep + 255) / 256, 256, 0, stream>>>(W1, W2, W3, cws, W1f, W2f, W3f);

    sf_stft_fuse<<<BATCH, 512, 0, stream>>>(x, sw, cws, h0);

    // GEMM1: 2048x1024x2176, 64x64 tiles -> 512 blocks
    sf_gemm_flat<4, 4, 1><<<dim3(H1 / 64, BATCH / 64), 64, 0, stream>>>(h0, W1f, b1, h1, BATCH, H1, FEATP);
    // GEMM2: 2048x512x1024, 64x32 tiles -> 512 blocks
    sf_gemm_flat<4, 2, 1><<<dim3(H2 / 32, BATCH / 64), 64, 0, stream>>>(h1, W2f, b2, h2, BATCH, H2, H1);
    // GEMM3: 2048x256x512, 32x32 tiles -> 512 blocks
    sf_gemm_flat<2, 2, 1><<<dim3(H3 / 32, BATCH / 32), 64, 0, stream>>>(h2, W3f, b3, h3, BATCH, H3, H2);
    sf_final<<<(BATCH * NOUT + 255) / 256, 256, 0, stream>>>(h3, W4, b4, out);
}